// Round 2
// baseline (769.149 us; speedup 1.0000x reference)
//
#include <hip/hip_runtime.h>
#include <stdint.h>

// Problem dims (fixed by reference): B=8, S=1024, D=1024, H=16, HD=64.
// All I/O tensors are float32 (per reference); mask is int32.
#define BB 8
#define SS 1024
#define DD 1024
#define HH 16
#define HDIM 64

typedef _Float16 half8 __attribute__((ext_vector_type(8)));
typedef _Float16 half4 __attribute__((ext_vector_type(4)));
typedef float   float4v __attribute__((ext_vector_type(4)));
typedef float   float8v __attribute__((ext_vector_type(8)));
typedef int     int4v   __attribute__((ext_vector_type(4)));

#define AS1(p) ((__attribute__((address_space(1))) void*)(p))
#define AS3(p) ((__attribute__((address_space(3))) void*)(p))

// ---------------------------------------------------------------------------
// f32 -> f16 conversion, multi-segment (grid.y selects segment)
// ---------------------------------------------------------------------------
struct CvtArgs {
    const float* src[5];
    _Float16*    dst[5];
    long long    n[5];
};

__global__ __launch_bounds__(256) void cvt_f32_f16(CvtArgs a) {
    int seg = blockIdx.y;
    long long base = ((long long)blockIdx.x * 256 + threadIdx.x) * 8;
    if (base >= a.n[seg]) return;
    float8v u = *(const float8v*)(a.src[seg] + base);
    half8 h;
#pragma unroll
    for (int i = 0; i < 8; ++i) h[i] = (_Float16)u[i];
    *(half8*)(a.dst[seg] + base) = h;
}

// ---------------------------------------------------------------------------
// GEMM: C[m,n] = sum_k A[m,k]*W[n,k] + bias[n]   (A: Mx1024 f16, W: 1024x1024 f16)
// m97 recipe: 128x128 tile, BK=64, 4 waves (2x2 of 64x64), 16x16x32 f16 MFMA,
// global_load_lds width-16 staging, 2-barrier K-loop.
// MODE 0: out f16 laid out (B,H,S,HD)       (q, k projections)
// MODE 1: out f16 laid out (B,H,HD,S) = vT  (v projection)
// MODE 2: out f32 row-major (M x 1024)      (final output projection -> d_out)
// ---------------------------------------------------------------------------
template <int MODE>
__global__ __launch_bounds__(256) void gemm_bt(
    const _Float16* __restrict__ A,
    const _Float16* __restrict__ W,
    const float* __restrict__ bias,
    void* __restrict__ out)
{
    constexpr int K = 1024, BM = 128, BK = 64;
    __shared__ _Float16 As[BM * BK];
    __shared__ _Float16 Bs[BM * BK];

    const int tid  = threadIdx.x;
    const int lane = tid & 63;
    const int wave = tid >> 6;
    const int wm = wave >> 1, wn = wave & 1;
    const int m0 = blockIdx.x * BM;
    const int n0 = blockIdx.y * BM;

    float4v acc[4][4] = {};

    for (int kt = 0; kt < K; kt += BK) {
#pragma unroll
        for (int i = 0; i < 4; ++i) {
            int flat = ((wave * 4 + i) * 64 + lane) * 8;  // element index in tile
            int r = flat >> 6, c = flat & 63;
            const _Float16* ga = A + (long long)(m0 + r) * K + kt + c;
            const _Float16* gb = W + (long long)(n0 + r) * K + kt + c;
            __builtin_amdgcn_global_load_lds(AS1(ga), AS3(&As[flat]), 16, 0, 0);
            __builtin_amdgcn_global_load_lds(AS1(gb), AS3(&Bs[flat]), 16, 0, 0);
        }
        __syncthreads();
#pragma unroll
        for (int kk = 0; kk < BK; kk += 32) {
            half8 af[4], bf[4];
#pragma unroll
            for (int t = 0; t < 4; ++t) {
                af[t] = *(const half8*)&As[(wm * 64 + t * 16 + (lane & 15)) * BK + kk + (lane >> 4) * 8];
                bf[t] = *(const half8*)&Bs[(wn * 64 + t * 16 + (lane & 15)) * BK + kk + (lane >> 4) * 8];
            }
#pragma unroll
            for (int mt = 0; mt < 4; ++mt)
#pragma unroll
                for (int nt = 0; nt < 4; ++nt)
                    acc[mt][nt] = __builtin_amdgcn_mfma_f32_16x16x32_f16(af[mt], bf[nt], acc[mt][nt], 0, 0, 0);
        }
        __syncthreads();
    }

    // Epilogue. C/D layout (m89-verified): row = (lane>>4)*4 + reg, col = lane&15.
#pragma unroll
    for (int mt = 0; mt < 4; ++mt) {
#pragma unroll
        for (int nt = 0; nt < 4; ++nt) {
            int n  = n0 + wn * 64 + nt * 16 + (lane & 15);
            int mb = m0 + wm * 64 + mt * 16 + (lane >> 4) * 4;
            float bn = bias[n];
            if constexpr (MODE == 0) {
                _Float16* o = (_Float16*)out;
                int b = mb >> 10, s = mb & 1023, h = n >> 6, hd = n & 63;
                long long idx = ((long long)(b * 16 + h) * 1024 + s) * 64 + hd;
#pragma unroll
                for (int i = 0; i < 4; ++i)
                    o[idx + (long long)i * 64] = (_Float16)(acc[mt][nt][i] + bn);
            } else if constexpr (MODE == 1) {
                _Float16* o = (_Float16*)out;
                int b = mb >> 10, s = mb & 1023, h = n >> 6, hd = n & 63;
                long long idx = ((long long)(b * 16 + h) * 64 + hd) * 1024 + s;
                half4 hv;
#pragma unroll
                for (int i = 0; i < 4; ++i) hv[i] = (_Float16)(acc[mt][nt][i] + bn);
                *(half4*)&o[idx] = hv;   // s is multiple of 4 -> 8B aligned
            } else {
                float* o = (float*)out;  // f32 d_out
#pragma unroll
                for (int i = 0; i < 4; ++i)
                    o[(long long)(mb + i) * 1024 + n] = acc[mt][nt][i] + bn;
            }
        }
    }
}

// ---------------------------------------------------------------------------
// Flash attention. Grid: B*H*(S/64) blocks, 4 waves/block, each wave owns 16
// q-rows. No LDS, no barriers. Computes S^T via mfma(A=K, B=Q^T); the S^T C/D
// fragment IS the A-operand fragment of P for the 16x16x16 PV MFMA.
// ---------------------------------------------------------------------------
__global__ __launch_bounds__(256) void attn_kernel(
    const _Float16* __restrict__ qw,   // (B*H, S, HD) f16
    const _Float16* __restrict__ kw,   // (B*H, S, HD) f16
    const _Float16* __restrict__ vT,   // (B*H, HD, S) f16
    const int* __restrict__ mask,      // (B, S, S) int32
    const float* __restrict__ syn,     // (H, S, S) f32
    const float* __restrict__ alpha_p, // (1,) f32
    _Float16* __restrict__ ao)         // (B, S, D) f16
{
    const int lane = threadIdx.x & 63;
    const int wave = threadIdx.x >> 6;
    const int bid  = blockIdx.x;
    const int b  = bid >> 8;           // 256 blocks per batch (16 h * 16 qtiles)
    const int h  = (bid >> 4) & 15;
    const int q0 = ((bid & 15) * 4 + wave) * 16;
    const int bh = b * 16 + h;

    const float ap = alpha_p[0];
    const float alpha = 1.0f / (1.0f + __expf(-ap));
    const float nalpha = 1.0f - alpha;
    const float scale = 0.125f * alpha;   // alpha / sqrt(HD)

    // Q fragments (B-operand of 16x16x32): lane holds Q[q0+(l&15)][(l>>4)*8+j (+32)]
    const _Float16* qbase = qw + ((long long)bh * SS + q0 + (lane & 15)) * HDIM + (lane >> 4) * 8;
    const half8 qf0 = *(const half8*)(qbase);
    const half8 qf1 = *(const half8*)(qbase + 32);

    float4v o[4] = {};
    float mrun = -3e38f, lrun = 0.f;

    const long long krow    = (long long)bh * SS * HDIM;
    const long long vrow    = (long long)bh * HDIM * SS;
    const long long maskrow = ((long long)b * SS + q0 + (lane & 15)) * SS + (lane >> 4) * 4;
    const long long synrow  = ((long long)h * SS + q0 + (lane & 15)) * SS + (lane >> 4) * 4;

    for (int t = 0; t < 16; ++t) {
        const int kb = t * 64;
        float4v st[4];
#pragma unroll
        for (int ks = 0; ks < 4; ++ks) {
            const _Float16* kp = kw + krow + (long long)(kb + ks * 16 + (lane & 15)) * HDIM + (lane >> 4) * 8;
            half8 ka0 = *(const half8*)kp;
            half8 ka1 = *(const half8*)(kp + 32);
            float4v s4 = {};
            s4 = __builtin_amdgcn_mfma_f32_16x16x32_f16(ka0, qf0, s4, 0, 0, 0);
            s4 = __builtin_amdgcn_mfma_f32_16x16x32_f16(ka1, qf1, s4, 0, 0, 0);
            st[ks] = s4;   // lane holds S[q=l&15][key=kb+ks*16+(l>>4)*4+i]
        }
        // blend with syn, apply mask, track tile max
        float tmax = -3e38f;
#pragma unroll
        for (int ks = 0; ks < 4; ++ks) {
            int4v    mv = *(const int4v*)&mask[maskrow + kb + ks * 16];
            float4v  sv = *(const float4v*)&syn[synrow + kb + ks * 16];
#pragma unroll
            for (int i = 0; i < 4; ++i) {
                float sc = scale * st[ks][i] + nalpha * sv[i];
                sc = (mv[i] == 0) ? -1e9f : sc;
                st[ks][i] = sc;
                tmax = fmaxf(tmax, sc);
            }
        }
        // reduce max over key dim: lane groups via xor 16,32
        tmax = fmaxf(tmax, __shfl_xor(tmax, 16));
        tmax = fmaxf(tmax, __shfl_xor(tmax, 32));
        const float mnew = fmaxf(mrun, tmax);
        const float corr = __expf(mrun - mnew);

        float psum = 0.f;
        half4 pf[4];
#pragma unroll
        for (int ks = 0; ks < 4; ++ks)
#pragma unroll
            for (int i = 0; i < 4; ++i) {
                float p = __expf(st[ks][i] - mnew);
                psum += p;
                pf[ks][i] = (_Float16)p;
            }
        psum += __shfl_xor(psum, 16);
        psum += __shfl_xor(psum, 32);
        lrun = lrun * corr + psum;
        mrun = mnew;

        // rescale O: O rows are q=(l>>4)*4+i; corr for q-row q lives at lane q (q<16)
        float cr[4];
#pragma unroll
        for (int i = 0; i < 4; ++i) cr[i] = __shfl(corr, ((lane >> 4) << 2) + i);
#pragma unroll
        for (int n = 0; n < 4; ++n) {
#pragma unroll
            for (int i = 0; i < 4; ++i) o[n][i] *= cr[i];
        }
        // PV: O[q][hd] += P * V.  A = pf (already in A-layout), B from vT.
#pragma unroll
        for (int ks = 0; ks < 4; ++ks) {
#pragma unroll
            for (int n = 0; n < 4; ++n) {
                half4 vf = *(const half4*)&vT[vrow + (long long)(n * 16 + (lane & 15)) * SS + kb + ks * 16 + (lane >> 4) * 4];
                o[n] = __builtin_amdgcn_mfma_f32_16x16x16f16(pf[ks], vf, o[n], 0, 0, 0);
            }
        }
    }

    float rs[4];
#pragma unroll
    for (int i = 0; i < 4; ++i) {
        float li = __shfl(lrun, ((lane >> 4) << 2) + i);
        rs[i] = 1.0f / li;
    }
#pragma unroll
    for (int n = 0; n < 4; ++n) {
#pragma unroll
        for (int i = 0; i < 4; ++i) {
            int qrow = q0 + (lane >> 4) * 4 + i;
            long long idx = ((long long)b * SS + qrow) * DD + h * 64 + n * 16 + (lane & 15);
            ao[idx] = (_Float16)(o[n][i] * rs[i]);
        }
    }
}

// ---------------------------------------------------------------------------
// Launcher. ws layout (f16 elements), total 36M f16 = 72 MB:
//   [0,8M)    xbuf (reused for converted query/key_in/value; later ao)
//   [8M,12M)  Wq,Wk,Wv,Wo f16 (1M each)
//   [12M,20M) q  (B,H,S,HD)
//   [20M,28M) k  (B,H,S,HD)
//   [28M,36M) vT (B,H,HD,S)
// ---------------------------------------------------------------------------
extern "C" void kernel_launch(void* const* d_in, const int* in_sizes, int n_in,
                              void* d_out, int out_size, void* d_ws, size_t ws_size,
                              hipStream_t stream) {
    const float* query  = (const float*)d_in[0];
    const float* key_in = (const float*)d_in[1];
    const float* value  = (const float*)d_in[2];
    const int*   mask   = (const int*)d_in[3];
    const float* Wq = (const float*)d_in[4];
    const float* bq = (const float*)d_in[5];
    const float* Wk = (const float*)d_in[6];
    const float* bk = (const float*)d_in[7];
    const float* Wv = (const float*)d_in[8];
    const float* bv = (const float*)d_in[9];
    const float* Wo = (const float*)d_in[10];
    const float* bo = (const float*)d_in[11];
    const float* syn = (const float*)d_in[12];
    const float* alp = (const float*)d_in[13];

    const long long XN = (long long)BB * SS * DD;   // 8M
    const long long WN = (long long)DD * DD;        // 1M

    _Float16* ws   = (_Float16*)d_ws;
    _Float16* xbuf = ws;
    _Float16* wqf  = ws + XN;
    _Float16* wkf  = wqf + WN;
    _Float16* wvf  = wkf + WN;
    _Float16* wof  = wvf + WN;
    _Float16* qws  = wof + WN;
    _Float16* kws  = qws + XN;
    _Float16* vTws = kws + XN;
    _Float16* ao   = xbuf;   // xbuf dead after v projection

    dim3 blk(256);
    dim3 ggrid(64, 8);       // 8192/128 x 1024/128

    // L1: convert query + all 4 weights
    CvtArgs a1;
    a1.src[0] = query;  a1.dst[0] = xbuf; a1.n[0] = XN;
    a1.src[1] = Wq;     a1.dst[1] = wqf;  a1.n[1] = WN;
    a1.src[2] = Wk;     a1.dst[2] = wkf;  a1.n[2] = WN;
    a1.src[3] = Wv;     a1.dst[3] = wvf;  a1.n[3] = WN;
    a1.src[4] = Wo;     a1.dst[4] = wof;  a1.n[4] = WN;
    cvt_f32_f16<<<dim3(4096, 5), blk, 0, stream>>>(a1);
    gemm_bt<0><<<ggrid, blk, 0, stream>>>(xbuf, wqf, bq, qws);

    CvtArgs a2 = a1; a2.src[0] = key_in;
    cvt_f32_f16<<<dim3(4096, 1), blk, 0, stream>>>(a2);
    gemm_bt<0><<<ggrid, blk, 0, stream>>>(xbuf, wkf, bk, kws);

    CvtArgs a3 = a1; a3.src[0] = value;
    cvt_f32_f16<<<dim3(4096, 1), blk, 0, stream>>>(a3);
    gemm_bt<1><<<ggrid, blk, 0, stream>>>(xbuf, wvf, bv, vTws);

    attn_kernel<<<dim3(2048), blk, 0, stream>>>(qws, kws, vTws, mask, syn, alp, ao);

    gemm_bt<2><<<ggrid, blk, 0, stream>>>(ao, wof, bo, d_out);
}

// Round 4
// 615.026 us; speedup vs baseline: 1.2506x; 1.2506x over previous
//
#include <hip/hip_runtime.h>
#include <stdint.h>

// Problem dims (fixed by reference): B=8, S=1024, D=1024, H=16, HD=64.
// All I/O tensors are float32 (per reference); mask is int32.
#define BB 8
#define SS 1024
#define DD 1024
#define HH 16
#define HDIM 64

typedef _Float16 half8 __attribute__((ext_vector_type(8)));
typedef _Float16 half4 __attribute__((ext_vector_type(4)));
typedef float   float4v __attribute__((ext_vector_type(4)));
typedef float   float8v __attribute__((ext_vector_type(8)));

#define AS1(p) ((__attribute__((address_space(1))) void*)(p))
#define AS3(p) ((__attribute__((address_space(3))) void*)(p))

// ---------------------------------------------------------------------------
// f32 -> f16 conversion, multi-segment (grid.y selects segment).
// scaled[seg] != 0 => multiply by (1 - sigmoid(alp[0]))  (syn pre-blend scale)
// ---------------------------------------------------------------------------
struct CvtArgs {
    const float* src[6];
    _Float16*    dst[6];
    long long    n[6];
    int          scaled[6];
    const float* alp;
};

__global__ __launch_bounds__(256) void cvt_f32_f16(CvtArgs a) {
    int seg = blockIdx.y;
    long long base = ((long long)blockIdx.x * 256 + threadIdx.x) * 8;
    if (base >= a.n[seg]) return;
    float s = 1.0f;
    if (a.scaled[seg]) s = 1.0f - 1.0f / (1.0f + __expf(-a.alp[0]));
    float8v u = *(const float8v*)(a.src[seg] + base);
    half8 h;
#pragma unroll
    for (int i = 0; i < 8; ++i) h[i] = (_Float16)(u[i] * s);
    *(half8*)(a.dst[seg] + base) = h;
}

// ---------------------------------------------------------------------------
// Pack mask (B,S,S) int32 -> bitmask (B,S,S/64) u64. One wave packs 64 keys.
// ---------------------------------------------------------------------------
__global__ __launch_bounds__(256) void pack_mask(const int* __restrict__ mask,
                                                 unsigned long long* __restrict__ bits) {
    long long gid = (long long)blockIdx.x * 256 + threadIdx.x;
    int m = mask[gid];
    unsigned long long bal = __ballot(m != 0);
    if ((threadIdx.x & 63) == 0) bits[gid >> 6] = bal;
}

// ---------------------------------------------------------------------------
// GEMM: C[m,n] = sum_k A[m,k]*W[n,k] + bias[n]   (A: Mx1024 f16, W: 1024x1024 f16)
// m97 recipe: 128x128 tile, BK=64, 4 waves (2x2 of 64x64), 16x16x32 f16 MFMA.
// MODE 0: out f16 (B,H,S,HD); SCALEQ multiplies by sigmoid(alp)/8 (q proj)
// MODE 1: out f16 (B,H,HD,S) = vT  (v projection)
// MODE 2: out f32 row-major (M x 1024)  (final output projection -> d_out)
// ---------------------------------------------------------------------------
template <int MODE, bool SCALEQ>
__global__ __launch_bounds__(256) void gemm_bt(
    const _Float16* __restrict__ A,
    const _Float16* __restrict__ W,
    const float* __restrict__ bias,
    void* __restrict__ out,
    const float* __restrict__ alp)
{
    constexpr int K = 1024, BM = 128, BK = 64;
    __shared__ _Float16 As[BM * BK];
    __shared__ _Float16 Bs[BM * BK];

    const int tid  = threadIdx.x;
    const int lane = tid & 63;
    const int wave = tid >> 6;
    const int wm = wave >> 1, wn = wave & 1;
    const int m0 = blockIdx.x * BM;
    const int n0 = blockIdx.y * BM;

    float4v acc[4][4] = {};

    for (int kt = 0; kt < K; kt += BK) {
#pragma unroll
        for (int i = 0; i < 4; ++i) {
            int flat = ((wave * 4 + i) * 64 + lane) * 8;  // element index in tile
            int r = flat >> 6, c = flat & 63;
            const _Float16* ga = A + (long long)(m0 + r) * K + kt + c;
            const _Float16* gb = W + (long long)(n0 + r) * K + kt + c;
            __builtin_amdgcn_global_load_lds(AS1(ga), AS3(&As[flat]), 16, 0, 0);
            __builtin_amdgcn_global_load_lds(AS1(gb), AS3(&Bs[flat]), 16, 0, 0);
        }
        __syncthreads();
#pragma unroll
        for (int kk = 0; kk < BK; kk += 32) {
            half8 af[4], bf[4];
#pragma unroll
            for (int t = 0; t < 4; ++t) {
                af[t] = *(const half8*)&As[(wm * 64 + t * 16 + (lane & 15)) * BK + kk + (lane >> 4) * 8];
                bf[t] = *(const half8*)&Bs[(wn * 64 + t * 16 + (lane & 15)) * BK + kk + (lane >> 4) * 8];
            }
#pragma unroll
            for (int mt = 0; mt < 4; ++mt)
#pragma unroll
                for (int nt = 0; nt < 4; ++nt)
                    acc[mt][nt] = __builtin_amdgcn_mfma_f32_16x16x32_f16(af[mt], bf[nt], acc[mt][nt], 0, 0, 0);
        }
        __syncthreads();
    }

    float qscale = 1.0f;
    if constexpr (SCALEQ) qscale = 0.125f / (1.0f + __expf(-alp[0]));

    // Epilogue. C/D layout: row = (lane>>4)*4 + reg, col = lane&15.
#pragma unroll
    for (int mt = 0; mt < 4; ++mt) {
#pragma unroll
        for (int nt = 0; nt < 4; ++nt) {
            int n  = n0 + wn * 64 + nt * 16 + (lane & 15);
            int mb = m0 + wm * 64 + mt * 16 + (lane >> 4) * 4;
            float bn = bias[n];
            if constexpr (MODE == 0) {
                _Float16* o = (_Float16*)out;
                int b = mb >> 10, s = mb & 1023, h = n >> 6, hd = n & 63;
                long long idx = ((long long)(b * 16 + h) * 1024 + s) * 64 + hd;
#pragma unroll
                for (int i = 0; i < 4; ++i)
                    o[idx + (long long)i * 64] = (_Float16)((acc[mt][nt][i] + bn) * qscale);
            } else if constexpr (MODE == 1) {
                _Float16* o = (_Float16*)out;
                int b = mb >> 10, s = mb & 1023, h = n >> 6, hd = n & 63;
                long long idx = ((long long)(b * 16 + h) * 64 + hd) * 1024 + s;
                half4 hv;
#pragma unroll
                for (int i = 0; i < 4; ++i) hv[i] = (_Float16)(acc[mt][nt][i] + bn);
                *(half4*)&o[idx] = hv;
            } else {
                float* o = (float*)out;  // f32 d_out
#pragma unroll
                for (int i = 0; i < 4; ++i)
                    o[(long long)(mb + i) * 1024 + n] = acc[mt][nt][i] + bn;
            }
        }
    }
}

// ---------------------------------------------------------------------------
// Flash attention. Grid: B*H*(S/128) = 1024 blocks, 4 waves/block, each wave
// owns 32 q-rows (two 16-row fragments sharing K and vT register loads).
// No LDS, no barriers. S^T via mfma(A=K, B=Q^T); S^T C/D fragment == A-operand
// fragment of P for the 16x16x16 PV MFMA. K-tiles register double-buffered.
// Q is pre-scaled by alpha/8 in projection; syn pre-scaled by (1-alpha).
// Mask comes in packed as 1 bit per (b,q,k).
// ---------------------------------------------------------------------------
__global__ __launch_bounds__(256) void attn_kernel(
    const _Float16* __restrict__ qw,   // (B*H, S, HD) f16, pre-scaled
    const _Float16* __restrict__ kw,   // (B*H, S, HD) f16
    const _Float16* __restrict__ vT,   // (B*H, HD, S) f16
    const unsigned long long* __restrict__ mbits, // (B, S, 16) packed mask
    const _Float16* __restrict__ synh, // (H, S, S) f16, pre-scaled by (1-alpha)
    _Float16* __restrict__ ao)         // (B, S, D) f16
{
    const int lane = threadIdx.x & 63;
    const int wave = threadIdx.x >> 6;
    const int bid  = blockIdx.x;
    const int b  = bid >> 7;           // 128 blocks per batch (16 h * 8 qtiles)
    const int h  = (bid >> 3) & 15;
    const int q0 = (bid & 7) * 128 + wave * 32;
    const int bh = b * 16 + h;

    // Q fragments (B-operand of 16x16x32): lane holds Q[q0+f*16+(l&15)][(l>>4)*8+j]
    half8 qf[2][2];
#pragma unroll
    for (int f = 0; f < 2; ++f) {
        const _Float16* qb = qw + ((long long)bh * SS + q0 + f * 16 + (lane & 15)) * HDIM + (lane >> 4) * 8;
        qf[f][0] = *(const half8*)qb;
        qf[f][1] = *(const half8*)(qb + 32);
    }

    float4v o[2][4] = {};
    float mrun[2] = {-3e38f, -3e38f};
    float lrun[2] = {0.f, 0.f};

    const _Float16* kbase = kw + (long long)bh * SS * HDIM;
    const _Float16* vbase = vT + (long long)bh * HDIM * SS;
    const unsigned long long* mb0 = mbits + ((long long)b * SS + q0 + (lane & 15)) * 16;
    const _Float16* syn0 = synh + ((long long)h * SS + q0 + (lane & 15)) * SS + ((lane >> 4) << 2);

    half8 kA[8], kB[8];

    auto loadK = [&](int kb, half8 (&dst)[8]) {
#pragma unroll
        for (int ks = 0; ks < 4; ++ks) {
            const _Float16* kp = kbase + (long long)(kb + ks * 16 + (lane & 15)) * HDIM + (lane >> 4) * 8;
            dst[2 * ks]     = *(const half8*)kp;
            dst[2 * ks + 1] = *(const half8*)(kp + 32);
        }
    };

    auto proc = [&](int kb, half8 (&kreg)[8]) {
        const int t = kb >> 6;
        unsigned long long bits[2];
        bits[0] = mb0[t];
        bits[1] = mb0[256 + t];
        half4 sv[2][4];
#pragma unroll
        for (int f = 0; f < 2; ++f)
#pragma unroll
            for (int ks = 0; ks < 4; ++ks)
                sv[f][ks] = *(const half4*)(syn0 + (long long)f * 16 * SS + kb + ks * 16);

        float4v st[2][4];
#pragma unroll
        for (int ks = 0; ks < 4; ++ks) {
#pragma unroll
            for (int f = 0; f < 2; ++f) {
                float4v s = {};
                s = __builtin_amdgcn_mfma_f32_16x16x32_f16(kreg[2 * ks],     qf[f][0], s, 0, 0, 0);
                s = __builtin_amdgcn_mfma_f32_16x16x32_f16(kreg[2 * ks + 1], qf[f][1], s, 0, 0, 0);
                st[f][ks] = s;   // S[q=l&15][key=kb+ks*16+(l>>4)*4+i]
            }
        }

        half4 pf[2][4];
#pragma unroll
        for (int f = 0; f < 2; ++f) {
            const unsigned long long bt = bits[f];
            float tmax = -3e38f;
#pragma unroll
            for (int ks = 0; ks < 4; ++ks)
#pragma unroll
                for (int i = 0; i < 4; ++i) {
                    float sc = st[f][ks][i] + (float)sv[f][ks][i];
                    int pos = ks * 16 + ((lane >> 4) << 2) + i;
                    sc = ((bt >> pos) & 1ull) ? sc : -1e9f;
                    st[f][ks][i] = sc;
                    tmax = fmaxf(tmax, sc);
                }
            tmax = fmaxf(tmax, __shfl_xor(tmax, 16));
            tmax = fmaxf(tmax, __shfl_xor(tmax, 32));
            const float mnew = fmaxf(mrun[f], tmax);
            const float corr = __expf(mrun[f] - mnew);
            float psum = 0.f;
#pragma unroll
            for (int ks = 0; ks < 4; ++ks)
#pragma unroll
                for (int i = 0; i < 4; ++i) {
                    float p = __expf(st[f][ks][i] - mnew);
                    psum += p;
                    pf[f][ks][i] = (_Float16)p;
                }
            psum += __shfl_xor(psum, 16);
            psum += __shfl_xor(psum, 32);
            lrun[f] = lrun[f] * corr + psum;
            mrun[f] = mnew;
            float cr[4];
#pragma unroll
            for (int i = 0; i < 4; ++i) cr[i] = __shfl(corr, ((lane >> 4) << 2) + i);
#pragma unroll
            for (int n = 0; n < 4; ++n)
#pragma unroll
                for (int i = 0; i < 4; ++i) o[f][n][i] *= cr[i];
        }

        // PV: vT frag loads shared by both q-fragments
#pragma unroll
        for (int ks = 0; ks < 4; ++ks)
#pragma unroll
            for (int n = 0; n < 4; ++n) {
                half4 vf = *(const half4*)&vbase[(long long)(n * 16 + (lane & 15)) * SS + kb + ks * 16 + ((lane >> 4) << 2)];
                o[0][n] = __builtin_amdgcn_mfma_f32_16x16x16f16(pf[0][ks], vf, o[0][n], 0, 0, 0);
                o[1][n] = __builtin_amdgcn_mfma_f32_16x16x16f16(pf[1][ks], vf, o[1][n], 0, 0, 0);
            }
    };

    loadK(0, kA);
    for (int t = 0; t < 16; t += 2) {
        loadK((t + 1) * 64, kB);
        proc(t * 64, kA);
        if (t + 2 < 16) loadK((t + 2) * 64, kA);
        proc((t + 1) * 64, kB);
    }

#pragma unroll
    for (int f = 0; f < 2; ++f) {
        float rs[4];
#pragma unroll
        for (int i = 0; i < 4; ++i) {
            float li = __shfl(lrun[f], ((lane >> 4) << 2) + i);
            rs[i] = 1.0f / li;
        }
#pragma unroll
        for (int n = 0; n < 4; ++n)
#pragma unroll
            for (int i = 0; i < 4; ++i) {
                int qrow = q0 + f * 16 + (lane >> 4) * 4 + i;
                long long idx = ((long long)b * SS + qrow) * DD + h * 64 + n * 16 + (lane & 15);
                ao[idx] = (_Float16)(o[f][n][i] * rs[i]);
            }
    }
}

// ---------------------------------------------------------------------------
// Launcher. ws layout (f16 elements):
//   [0,8M)     xbuf (converted query/key_in/value; later ao)
//   [8M,12M)   Wq,Wk,Wv,Wo f16 (1M each)
//   [12M,20M)  q  (B,H,S,HD)   pre-scaled by alpha/8
//   [20M,28M)  k  (B,H,S,HD)
//   [28M,36M)  vT (B,H,HD,S)
//   [36M,52M)  synh (H,S,S) f16 pre-scaled by (1-alpha)
//   [52M,+1MB) mbits (B,S,16) u64
// Total ~105 MB.
// ---------------------------------------------------------------------------
extern "C" void kernel_launch(void* const* d_in, const int* in_sizes, int n_in,
                              void* d_out, int out_size, void* d_ws, size_t ws_size,
                              hipStream_t stream) {
    const float* query  = (const float*)d_in[0];
    const float* key_in = (const float*)d_in[1];
    const float* value  = (const float*)d_in[2];
    const int*   mask   = (const int*)d_in[3];
    const float* Wq = (const float*)d_in[4];
    const float* bq = (const float*)d_in[5];
    const float* Wk = (const float*)d_in[6];
    const float* bk = (const float*)d_in[7];
    const float* Wv = (const float*)d_in[8];
    const float* bv = (const float*)d_in[9];
    const float* Wo = (const float*)d_in[10];
    const float* bo = (const float*)d_in[11];
    const float* syn = (const float*)d_in[12];
    const float* alp = (const float*)d_in[13];

    const long long XN = (long long)BB * SS * DD;   // 8M
    const long long WN = (long long)DD * DD;        // 1M
    const long long SN = (long long)HH * SS * SS;   // 16M

    _Float16* ws   = (_Float16*)d_ws;
    _Float16* xbuf = ws;
    _Float16* wqf  = ws + XN;
    _Float16* wkf  = wqf + WN;
    _Float16* wvf  = wkf + WN;
    _Float16* wof  = wvf + WN;
    _Float16* qws  = wof + WN;
    _Float16* kws  = qws + XN;
    _Float16* vTws = kws + XN;
    _Float16* synh = vTws + XN;
    unsigned long long* mbits = (unsigned long long*)(synh + SN);
    _Float16* ao   = xbuf;   // xbuf dead after v projection

    dim3 blk(256);
    dim3 ggrid(64, 8);       // 8192/128 x 1024/128

    // Convert query + all 4 weights + syn (scaled by 1-alpha)
    CvtArgs a1;
    a1.src[0] = query;  a1.dst[0] = xbuf; a1.n[0] = XN; a1.scaled[0] = 0;
    a1.src[1] = Wq;     a1.dst[1] = wqf;  a1.n[1] = WN; a1.scaled[1] = 0;
    a1.src[2] = Wk;     a1.dst[2] = wkf;  a1.n[2] = WN; a1.scaled[2] = 0;
    a1.src[3] = Wv;     a1.dst[3] = wvf;  a1.n[3] = WN; a1.scaled[3] = 0;
    a1.src[4] = Wo;     a1.dst[4] = wof;  a1.n[4] = WN; a1.scaled[4] = 0;
    a1.src[5] = syn;    a1.dst[5] = synh; a1.n[5] = SN; a1.scaled[5] = 1;
    a1.alp = alp;
    cvt_f32_f16<<<dim3(8192, 6), blk, 0, stream>>>(a1);

    pack_mask<<<dim3(32768), blk, 0, stream>>>(mask, mbits);

    gemm_bt<0, true><<<ggrid, blk, 0, stream>>>(xbuf, wqf, bq, qws, alp);

    CvtArgs a2 = a1; a2.src[0] = key_in;
    cvt_f32_f16<<<dim3(4096, 1), blk, 0, stream>>>(a2);
    gemm_bt<0, false><<<ggrid, blk, 0, stream>>>(xbuf, wkf, bk, kws, alp);

    CvtArgs a3 = a1; a3.src[0] = value;
    cvt_f32_f16<<<dim3(4096, 1), blk, 0, stream>>>(a3);
    gemm_bt<1, false><<<ggrid, blk, 0, stream>>>(xbuf, wvf, bv, vTws, alp);

    attn_kernel<<<dim3(1024), blk, 0, stream>>>(qws, kws, vTws, mbits, synh, ao);

    gemm_bt<2, false><<<ggrid, blk, 0, stream>>>(ao, wof, bo, d_out, alp);
}